// Round 1
// 488.215 us; speedup vs baseline: 1.0359x; 1.0359x over previous
//
#include <hip/hip_runtime.h>

// M=K=N=8192. x:[M,K] fp32, weight:[N,K] fp32.
// y[m] = 0.75 * dot(x[m,:], colsum(weight))  -> out is [M,1] fp32 (8192 floats)

#define M_DIM 8192
#define K_DIM 8192
#define N_DIM 8192

typedef float f32x4 __attribute__((ext_vector_type(4)));

// ---------------- Kernel 1: column-sum of weight over rows ----------------
// weight is [N, K] row-major. wcs[k] = sum_n weight[n*K + k].
// grid: (K/1024 = 8 column-groups, N/64 = 128 row-chunks), block = 256.
// Each thread owns one float4-column, sums 64 rows with two independent
// accumulator chains, then atomicAdds 4 partials into wcs (zeroed first).
// weight has zero reuse -> nontemporal loads keep it out of L2.
__global__ __launch_bounds__(256) void colsum_kernel(
    const float* __restrict__ w, float* __restrict__ wcs) {
    constexpr int ROWS = 64;
    const int col4 = blockIdx.x * 256 + threadIdx.x;   // float4-column index
    const int row0 = blockIdx.y * ROWS;
    const int stride4 = K_DIM / 4;
    const f32x4* __restrict__ p =
        (const f32x4*)w + (size_t)row0 * stride4 + col4;

    f32x4 a0 = (f32x4)0.f, a1 = (f32x4)0.f;
    #pragma unroll 8
    for (int r = 0; r < ROWS; r += 2) {
        f32x4 v0 = __builtin_nontemporal_load(p + (size_t)r * stride4);
        f32x4 v1 = __builtin_nontemporal_load(p + (size_t)(r + 1) * stride4);
        a0 += v0;
        a1 += v1;
    }
    a0 += a1;
    float* out = wcs + col4 * 4;
    atomicAdd(out + 0, a0.x);
    atomicAdd(out + 1, a0.y);
    atomicAdd(out + 2, a0.z);
    atomicAdd(out + 3, a0.w);
}

// ---------------- Kernel 2: per-row dot with wcs ----------------
// Wave-per-row: 2048 blocks x 4 waves = 8192 waves, one row of x each.
// No LDS, no __syncthreads -- pure wave-64 shuffle reduction.
// x has zero reuse -> nontemporal; wcs (32 KB) stays L2-hot via normal loads.
__global__ __launch_bounds__(256, 4) void rowdot_kernel(
    const float* __restrict__ x, const float* __restrict__ wcs,
    float* __restrict__ y) {
    const int wave = threadIdx.x >> 6;
    const int lane = threadIdx.x & 63;
    const int m = blockIdx.x * 4 + wave;
    const f32x4* __restrict__ x4 = (const f32x4*)(x + (size_t)m * K_DIM);
    const f32x4* __restrict__ w4 = (const f32x4*)wcs;

    f32x4 acc4 = (f32x4)0.f;
    #pragma unroll 8
    for (int j = 0; j < K_DIM / 4 / 64; ++j) {      // 32 iterations
        const int i = lane + 64 * j;
        f32x4 a = __builtin_nontemporal_load(x4 + i);
        f32x4 b = w4[i];
        acc4 += a * b;                               // 4 independent chains
    }
    float acc = acc4.x + acc4.y + acc4.z + acc4.w;
    #pragma unroll
    for (int off = 32; off > 0; off >>= 1)
        acc += __shfl_down(acc, off, 64);
    if (lane == 0) y[m] = 0.75f * acc;
}

extern "C" void kernel_launch(void* const* d_in, const int* in_sizes, int n_in,
                              void* d_out, int out_size, void* d_ws, size_t ws_size,
                              hipStream_t stream) {
    const float* x = (const float*)d_in[0];   // [M, K]
    const float* w = (const float*)d_in[1];   // [N, K]
    float* y = (float*)d_out;                 // [M] (== [M,1] flat)
    float* wcs = (float*)d_ws;                // [K] scratch

    // ws is poisoned 0xAA each call -> zero the accumulator (capture-safe).
    hipMemsetAsync(wcs, 0, K_DIM * sizeof(float), stream);

    dim3 g1(K_DIM / 1024, N_DIM / 64);        // 8 x 128 = 1024 blocks
    colsum_kernel<<<g1, 256, 0, stream>>>(w, wcs);

    rowdot_kernel<<<M_DIM / 4, 256, 0, stream>>>(x, wcs, y);
}